// Round 4
// baseline (5156.953 us; speedup 1.0000x reference)
//
#include <hip/hip_runtime.h>
#include <hip/hip_bf16.h>
#include <cstddef>

// ---------------------------------------------------------------------------
// AttentionLSTMDecoder on MI355X.  Round 6.
//  * R1-2: K/V folded to pos-affine scores, exp Taylor -> V-moment ratio;
//    Wo folded into W_ih0; one K=1088/1024 GEMM per layer per step.
//  * R3: persistent kernel.  R4: LDS XOR swizzle + flag barrier.  R5: group
//    barriers + bypass loads (regressed: MALL latency; FETCH unchanged =>
//    traffic is structural streaming, not fences).
//  * R6 (this): weights PINNED IN REGISTERS (256 blocks x 512thr, 1/CU; each
//    wave holds its B-frags forever -> B never re-read).  Groups = XCDs
//    (bid&7, 32 blocks, 80 seqs), runtime-verified via s_getreg(XCC_ID) with
//    permutation check; fast path uses sc0 (L2-coherent) loads + plain-store
//    flags; fallback to agent-scope (R5-verified) protocol if placement
//    check fails.  A-staging: 2-deep asm pipeline (vmcnt(3)+sched_barrier).
//    s3 hidden behind next step's h0-half K-chunks.
// ---------------------------------------------------------------------------

typedef _Float16 hx8 __attribute__((ext_vector_type(8)));
typedef float fx4 __attribute__((ext_vector_type(4)));
typedef unsigned long long u64;

#define NSEQ 640
#define TSTEPS 100
#define XC0 1088   // [x(576) | h0(512)]
#define XC1 1024   // [h0(512) | h1(512)]
#define NBLK 256   // persistent grid (1 block/CU)
#define FL 32      // u32 stride per barrier flag line (128B)
#define PUB (256*FL)

__device__ __forceinline__ float sigm(float x){ return 1.0f/(1.0f+__expf(-x)); }
__device__ __forceinline__ float tanh_(float x){
  x = fminf(fmaxf(x, -15.0f), 15.0f);
  float e = __expf(2.0f*x);
  return (e-1.0f)/(e+1.0f);
}
__device__ __forceinline__ float sel4(float a0,float a1,float a2,float a3,int h){
  float r = a0; r = (h==1)?a1:r; r = (h==2)?a2:r; r = (h==3)?a3:r; return r;
}

// cross-XCD-safe 16B load (agent scope -> coherence point). Slow path only.
__device__ __forceinline__ hx8 ldA(const _Float16* p){
  u64 q0 = __hip_atomic_load((u64*)p,     __ATOMIC_RELAXED, __HIP_MEMORY_SCOPE_AGENT);
  u64 q1 = __hip_atomic_load((u64*)p + 1, __ATOMIC_RELAXED, __HIP_MEMORY_SCOPE_AGENT);
  union { u64 q[2]; hx8 v; } u; u.q[0]=q0; u.q[1]=q1;
  return u.v;
}

// ---------------- fold kernels (one-time) ----------------

__global__ void kF1(const float* __restrict__ Wq, const float* __restrict__ Wc,
                    const float* __restrict__ bc, const float* __restrict__ bq,
                    float* __restrict__ u){
  int r = blockIdx.x*256 + threadIdx.x; if (r >= 512) return;
  float s0=0.f, s1=0.f, s2=0.f;
  for (int k=0;k<512;k++){
    float wq = Wq[r*512+k];
    s0 += wq*Wc[k*512+0];
    s1 += wq*Wc[k*512+1];
    s2 += wq*bc[k];
  }
  u[r]=s0; u[512+r]=s1; u[1024+r]=s2+bq[r];
}

__global__ __launch_bounds__(512) void kF2a(const float* __restrict__ Wk,
                                            const float* __restrict__ u,
                                            float* __restrict__ z){
  int ih = blockIdx.x; int kk = threadIdx.x;
  int i = ih>>2, h = ih&3;
  float s = 0.f;
  for (int d=0; d<128; d++)
    s += Wk[(h*128+d)*512 + kk] * u[i*512 + h*128 + d];
  z[ih*512+kk] = s;
}

__global__ __launch_bounds__(512) void kF2b(const float* __restrict__ z,
                                            const float* __restrict__ Wc,
                                            const float* __restrict__ bc,
                                            const float* __restrict__ bk,
                                            const float* __restrict__ u,
                                            float* __restrict__ Y, float* __restrict__ cc){
  const float scale = 0.08838834764831845f; // 1/sqrt(128)
  int ih = blockIdx.x; int j = threadIdx.x;
  int i = ih>>2, h = ih&3;
  float s = 0.f;
  for (int kk=0;kk<512;kk++) s += z[ih*512+kk]*Wc[kk*512+j];
  Y[ih*512+j] = s*scale;
  if (j==0){
    float t=0.f;
    for (int kk=0;kk<512;kk++) t += z[ih*512+kk]*bc[kk];
    for (int d=0;d<128;d++) t += u[i*512+h*128+d]*bk[h*128+d];
    cc[ih] = t*scale;
  }
}

__global__ void kFbv(const float* __restrict__ Wv, const float* __restrict__ bc,
                     const float* __restrict__ bv, float* __restrict__ bv2){
  int r = blockIdx.x*256 + threadIdx.x; if (r >= 512) return;
  float s = bv[r];
  for (int k=0;k<512;k++) s += Wv[r*512+k]*bc[k];
  bv2[r]=s;
}

// fp32 tiled GEMM: C[M,N] = A[:, aoff:aoff+K] @ B (64x64 tiles)
__global__ __launch_bounds__(256) void kgemm(const float* __restrict__ A, int lda, int aoff,
                                             const float* __restrict__ B, int ldb,
                                             float* __restrict__ C, int ldc, int K){
  __shared__ float As[64][16];
  __shared__ float Bs[16][64];
  int tid = threadIdx.x; int tx = tid&15, ty = tid>>4;
  int bx = blockIdx.x, by = blockIdx.y;
  float acc[4][4];
#pragma unroll
  for (int i=0;i<4;i++)
#pragma unroll
    for (int j=0;j<4;j++) acc[i][j]=0.f;
  for (int kk=0; kk<K; kk+=16){
#pragma unroll
    for (int e=0;e<4;e++){
      int id = tid*4+e;
      int r = id>>4, c = id&15;
      As[r][c] = A[(size_t)(by*64+r)*lda + aoff + kk + c];
      int r2 = id>>6, c2 = id&63;
      Bs[r2][c2] = B[(size_t)(kk+r2)*ldb + bx*64 + c2];
    }
    __syncthreads();
#pragma unroll
    for (int k=0;k<16;k++){
      float bvv[4];
#pragma unroll
      for (int j=0;j<4;j++) bvv[j] = Bs[k][tx*4+j];
#pragma unroll
      for (int i=0;i<4;i++){
        float av = As[ty*4+i][k];
#pragma unroll
        for (int j=0;j<4;j++) acc[i][j] += av*bvv[j];
      }
    }
    __syncthreads();
  }
#pragma unroll
  for (int i=0;i<4;i++)
#pragma unroll
    for (int j=0;j<4;j++)
      C[(size_t)(by*64+ty*4+i)*ldc + bx*64+tx*4+j] = acc[i][j];
}

__global__ void ktransp(const float* __restrict__ A, float* __restrict__ AT){
  int idx = blockIdx.x*256 + threadIdx.x;
  int r = idx>>9, c = idx&511;
  AT[c*512 + r] = A[idx];
}

// Bcat0 [2048][1088] = [Wih0[:,0:36] | Wmix | 0pad(28) | Whh0]
__global__ void kbcat0(const float* __restrict__ Wih0, const float* __restrict__ Wmix,
                       const float* __restrict__ Whh0, _Float16* __restrict__ B){
  int r = blockIdx.x;
  for (int c = threadIdx.x; c < 1088; c += 256){
    float v;
    if (c < 36) v = Wih0[r*548 + c];
    else if (c < 548) v = Wmix[r*512 + (c-36)];
    else if (c < 576) v = 0.f;
    else v = Whh0[r*512 + (c-576)];
    B[(size_t)r*1088 + c] = (_Float16)v;
  }
}

// Bcat1 [2048][1024] = [Wih1 | Whh1]
__global__ void kbcat1(const float* __restrict__ Wih1, const float* __restrict__ Whh1,
                       _Float16* __restrict__ B){
  int r = blockIdx.x;
  for (int c = threadIdx.x; c < 1024; c += 256){
    float v = (c < 512) ? Wih1[r*512 + c] : Whh1[r*512 + (c-512)];
    B[(size_t)r*1024 + c] = (_Float16)v;
  }
}

__global__ void kcast(const float* __restrict__ s, _Float16* __restrict__ d, int n){
  int i = blockIdx.x*256 + threadIdx.x;
  if (i < n) d[i] = (_Float16)s[i];
}

// b0 = bih0+bhh0+Wih0[:,36:]@bo ; b1 = bih1+bhh1
__global__ void kbias(const float* __restrict__ Wih0, const float* __restrict__ bo,
                      const float* __restrict__ bih0, const float* __restrict__ bhh0,
                      const float* __restrict__ bih1, const float* __restrict__ bhh1,
                      float* __restrict__ b0, float* __restrict__ b1){
  int j = blockIdx.x*256 + threadIdx.x; if (j >= 2048) return;
  float s = bih0[j]+bhh0[j];
  for (int k=0;k<512;k++) s += Wih0[j*548+36+k]*bo[k];
  b0[j]=s; b1[j]=bih1[j]+bhh1[j];
}

// ---------------- moment precompute ----------------

__global__ __launch_bounds__(256) void kP1(const float* __restrict__ ctx,
                                           const float* __restrict__ Y,
                                           const float* __restrict__ cc,
                                           float* __restrict__ W6){
  __shared__ float Yl[6144];
  __shared__ float ccl[12];
  int tid = threadIdx.x; int n = blockIdx.x;
  for (int e = tid; e < 6144; e += 256) Yl[e] = Y[e];
  if (tid < 12) ccl[tid] = cc[tid];
  __syncthreads();
  int wave = tid >> 6, lane = tid & 63;
  for (int it = 0; it < 50; ++it){
    int s = it*4 + wave;
    const float* cp = ctx + ((size_t)n*200 + s)*512;
    float p[12];
#pragma unroll
    for (int i=0;i<12;i++) p[i]=0.f;
    for (int c8 = 0; c8 < 8; ++c8){
      int col = c8*64 + lane;
      float v = cp[col];
#pragma unroll
      for (int i=0;i<12;i++) p[i] += v * Yl[i*512+col];
    }
#pragma unroll
    for (int m = 32; m; m >>= 1){
#pragma unroll
      for (int i=0;i<12;i++) p[i] += __shfl_xor(p[i], m, 64);
    }
    if (lane < 4){
      int h = lane;
      float a  = sel4(p[0],p[1],p[2], p[3], h) + ccl[h];
      float b  = sel4(p[4],p[5],p[6], p[7], h) + ccl[4+h];
      float cp_= sel4(p[8],p[9],p[10],p[11],h) + ccl[8+h];
      float beta = __expf(cp_);
      size_t base = (size_t)(n*24 + h*6)*200 + s;
      W6[base + 0*200] = beta;
      W6[base + 1*200] = beta*a;
      W6[base + 2*200] = beta*b;
      W6[base + 3*200] = beta*a*a*0.5f;
      W6[base + 4*200] = beta*a*b;
      W6[base + 5*200] = beta*b*b*0.5f;
    }
  }
}

__global__ __launch_bounds__(256) void kP2(const float* __restrict__ ctx,
                                           const float* __restrict__ W6,
                                           float* __restrict__ F, float* __restrict__ S){
  __shared__ float w6[4800];
  int tid = threadIdx.x, n = blockIdx.x;
  for (int e = tid; e < 4800; e += 256) w6[e] = W6[(size_t)n*4800 + e];
  __syncthreads();
  float a0[24], a1[24];
#pragma unroll
  for (int r=0;r<24;r++){ a0[r]=0.f; a1[r]=0.f; }
  const float* cp = ctx + (size_t)n*200*512;
  for (int s=0;s<200;s++){
    float v0 = cp[s*512 + tid];
    float v1 = cp[s*512 + tid + 256];
#pragma unroll
    for (int r=0;r<24;r++){ float w = w6[r*200+s]; a0[r]+=w*v0; a1[r]+=w*v1; }
  }
#pragma unroll
  for (int r=0;r<24;r++){
    F[(size_t)(n*24+r)*512 + tid]       = a0[r];
    F[(size_t)(n*24+r)*512 + tid + 256] = a1[r];
  }
  if (tid < 24){
    float s=0.f;
    for (int ss=0; ss<200; ss++) s += w6[tid*200+ss];
    S[n*24+tid]=s;
  }
}

__global__ __launch_bounds__(128) void kP3(const float* __restrict__ F,
                                           const float* __restrict__ WcvT,
                                           float* __restrict__ M){
  __shared__ float Fl[3072];
  int tid = threadIdx.x; int b = blockIdx.x; int n = b>>2, h = b&3;
  for (int e = tid; e < 3072; e += 128) Fl[e] = F[(size_t)(n*24 + h*6)*512 + e];
  __syncthreads();
  float acc[6];
#pragma unroll
  for (int i=0;i<6;i++) acc[i]=0.f;
  for (int k=0;k<512;k++){
    float w = WcvT[k*512 + h*128 + tid];
#pragma unroll
    for (int i=0;i<6;i++) acc[i] += w * Fl[i*512+k];
  }
#pragma unroll
  for (int i=0;i<6;i++) M[(size_t)(n*24+h*6+i)*128 + tid] = acc[i];
}

// ---------------- state init ----------------

__global__ __launch_bounds__(512) void kinit(const float* __restrict__ ball,
                    const int* __restrict__ roles, const float* __restrict__ remb,
                    _Float16* __restrict__ x0, _Float16* __restrict__ x1,
                    _Float16* __restrict__ hc0, _Float16* __restrict__ hc1,
                    float* __restrict__ c0, float* __restrict__ c1,
                    unsigned* __restrict__ bar){
  int n = blockIdx.x, tid = threadIdx.x;
  int b = n/10;
  int role = roles[n];
  for (int c = tid; c < XC0; c += 512){
    float v = 0.f;
    if (c>=2 && c<4)       v = ball[b*2 + (c-2)];
    else if (c>=4 && c<36) v = remb[role*32 + (c-4)];
    _Float16 hv = (_Float16)v;
    x0[(size_t)n*XC0+c] = hv;
    x1[(size_t)n*XC0+c] = hv;
  }
  for (int c = tid; c < XC1; c += 512){
    hc0[(size_t)n*XC1+c] = (_Float16)0.f;
    hc1[(size_t)n*XC1+c] = (_Float16)0.f;
  }
  if (tid < 512){
    c0[n*512+tid]=0.f; c1[n*512+tid]=0.f;
  }
  if (n < 256 && tid < FL) bar[n*FL + tid] = (tid==0) ? 16u : 0u;
  if (n == 0) bar[PUB + tid] = 0u;   // xcd publish area + verdict
}

// attention (Taylor-moment) for t=0 into xcat buf0
__global__ __launch_bounds__(128) void katt0(const float* __restrict__ ipos,
                                             const float* __restrict__ M,
                                             const float* __restrict__ S,
                                             const float* __restrict__ bv2,
                                             _Float16* __restrict__ x){
  int n = blockIdx.x, tid = threadIdx.x;
  float p0 = ipos[n*2], p1 = ipos[n*2+1];
  if (tid==0){ x[(size_t)n*XC0]=(_Float16)p0; x[(size_t)n*XC0+1]=(_Float16)p1; }
  float fa=p0*p0, fb=p0*p1, fc=p1*p1;
  for (int hd = tid; hd < 512; hd += 128){
    int h = hd>>7;
    int sb = n*24 + h*6;
    float den = S[sb] + p0*S[sb+1] + p1*S[sb+2] + fa*S[sb+3] + fb*S[sb+4] + fc*S[sb+5];
    const float* mp = M + (size_t)sb*128 + (hd&127);
    float num = mp[0] + p0*mp[128] + p1*mp[256] + fa*mp[384] + fb*mp[512] + fc*mp[640];
    x[(size_t)n*XC0 + 36 + hd] = (_Float16)(num/den + bv2[hd]);
  }
}

// =================== R5 multi-launch fallback kernels =====================
// (verified in earlier rounds; used only if the persistent kernel can't run)

template<int NC>
__device__ __forceinline__ void gates_body_ml(
    const _Float16* __restrict__ A, int lda,
    const _Float16* __restrict__ B,
    const float* __restrict__ bias, float* __restrict__ cst,
    _Float16* __restrict__ h1p, int ldh1, int co1,
    _Float16* __restrict__ h2p, int ldh2, int co2,
    int bx, _Float16* sbase, float (*eps)[32][16]){
  int tid = threadIdx.x, w = tid>>6, lane = tid&63;
  int lr = lane&15, lq = lane>>4;
  int mblk = bx>>5, jb = bx&31;
  int m0 = mblk*32, j0 = jb*16;
  int li = lane>>3, lc = lane&7;
  const _Float16* gA  = A + (size_t)(m0 + w*8 + li)*lda + lc*8;
  const _Float16* gB0 = B + (size_t)(w*512 + j0 + li)*lda + lc*8;
  const _Float16* gB1 = B + (size_t)(w*512 + j0 + 8 + li)*lda + lc*8;
  int sA  = (w*8 + li)*64        + ((lc ^ li)<<3);
  int sB0 = 2048 + (w*16 + li)*64 + ((lc ^ li)<<3);
  int sB1 = 2048 + (w*16 + 8 + li)*64 + ((lc ^ li)<<3);
  int ra7 = lr & 7;
  int fA00 = lr*64        + (((lq  ) ^ ra7)<<3);
  int fA01 = lr*64        + (((lq+4) ^ ra7)<<3);
  int fA10 = (16+lr)*64   + (((lq  ) ^ ra7)<<3);
  int fA11 = (16+lr)*64   + (((lq+4) ^ ra7)<<3);
  int fB0  = 2048 + (w*16+lr)*64 + (((lq  ) ^ ra7)<<3);
  int fB1  = 2048 + (w*16+lr)*64 + (((lq+4) ^ ra7)<<3);
  hx8 pA[2], pB0[2], pB1[2];
#pragma unroll
  for (int i=0;i<2;i++){
    int k = i*64;
    pA[i]  = ldA(gA + k);
    pB0[i] = *(const hx8*)(gB0 + k);
    pB1[i] = *(const hx8*)(gB1 + k);
  }
  fx4 ac0={0.f,0.f,0.f,0.f}, ac1={0.f,0.f,0.f,0.f};
#pragma unroll
  for (int c=0; c<NC; ++c){
    const int s = c & 1;
    _Float16* sb = sbase + (c&1)*6144;
    *(hx8*)(sb + sA)  = pA[s];
    *(hx8*)(sb + sB0) = pB0[s];
    *(hx8*)(sb + sB1) = pB1[s];
    __syncthreads();
    if (c+2 < NC){
      int k = (c+2)*64;
      pA[s]  = ldA(gA + k);
      pB0[s] = *(const hx8*)(gB0 + k);
      pB1[s] = *(const hx8*)(gB1 + k);
    }
    hx8 b0 = *(const hx8*)(sb + fB0);
    hx8 a0 = *(const hx8*)(sb + fA00);
    hx8 a1 = *(const hx8*)(sb + fA10);
    ac0 = __builtin_amdgcn_mfma_f32_16x16x32_f16(a0, b0, ac0, 0,0,0);
    ac1 = __builtin_amdgcn_mfma_f32_16x16x32_f16(a1, b0, ac1, 0,0,0);
    hx8 b1  = *(const hx8*)(sb + fB1);
    hx8 a0b = *(const hx8*)(sb + fA01);
    hx8 a1b = *(const hx8*)(sb + fA11);
    ac0 = __builtin_amdgcn_mfma_f32_16x16x32_f16(a0b, b1, ac0, 0,0,0);
    ac1 = __builtin_amdgcn_mfma_f32_16x16x32_f16(a1b, b1, ac1, 0,0,0);
    __syncthreads();
  }
#pragma unroll
  for (int r=0;r<4;r++){
    eps[w][lq*4+r][lr]    = ac0[r];
    eps[w][16+lq*4+r][lr] = ac1[r];
  }
  __syncthreads();
#pragma unroll
  for (int e=0;e<2;e++){
    int idx = e*256 + tid;
    int ml = idx>>4, j = idx&15;
    float gi = eps[0][ml][j] + bias[       j0+j];
    float gf = eps[1][ml][j] + bias[ 512 + j0+j];
    float gg = eps[2][ml][j] + bias[1024 + j0+j];
    float go = eps[3][ml][j] + bias[1536 + j0+j];
    int ci = (m0+ml)*512 + j0 + j;
    float c_ = cst[ci];
    float cn = sigm(gf)*c_ + sigm(gi)*tanh_(gg);
    float hn = sigm(go)*tanh_(cn);
    cst[ci] = cn;
    _Float16 hh = (_Float16)hn;
    h1p[(size_t)(m0+ml)*ldh1 + co1 + j0 + j] = hh;
    if (h2p) h2p[(size_t)(m0+ml)*ldh2 + co2 + j0 + j] = hh;
  }
}

template<int NC>
__global__ __launch_bounds__(256) void kgates(
    const _Float16* A, int lda, const _Float16* B,
    const float* bias, float* cst,
    _Float16* h1p, int ldh1, int co1,
    _Float16* h2p, int ldh2, int co2){
  __shared__ __align__(16) char smem[32768];
  gates_body_ml<NC>(A, lda, B, bias, cst, h1p, ldh1, co1, h2p, ldh2, co2,
                    blockIdx.x, (_Float16*)smem, (float(*)[32][16])(smem + 24576));
}

__global__ __launch_bounds__(256) void ks3b(const _Float16* __restrict__ h1, int ldh,
    const _Float16* __restrict__ Wf1, const float* __restrict__ bf1,
    const float* __restrict__ Wf2, const float* __restrict__ bf2,
    const float* __restrict__ M, const float* __restrict__ S,
    const float* __restrict__ bv2, _Float16* __restrict__ xn,
    float* __restrict__ out, int t){
  __shared__ float hid[16][264];
  __shared__ float posL[16][2];
  __shared__ float denL[16][4];
  int tid = threadIdx.x, w = tid>>6, lane = tid&63;
  int lr = lane&15, lq = lane>>4;
  int n0 = blockIdx.x*16;
  fx4 acc[4];
#pragma unroll
  for (int c=0;c<4;c++) acc[c] = (fx4){0.f,0.f,0.f,0.f};
  {
    const _Float16* ap = h1 + (size_t)(n0+lr)*ldh + lq*8;
    for (int ks=0; ks<16; ks++){
      hx8 a = ldA(ap + ks*32);
#pragma unroll
      for (int c=0;c<4;c++){
        const _Float16* bp = Wf1 + (size_t)(w*64 + c*16 + lr)*512 + ks*32 + lq*8;
        acc[c] = __builtin_amdgcn_mfma_f32_16x16x32_f16(a, *(const hx8*)bp, acc[c], 0,0,0);
      }
    }
  }
#pragma unroll
  for (int c=0;c<4;c++)
#pragma unroll
    for (int r=0;r<4;r++){
      int col = w*64 + c*16 + lr;
      hid[lq*4+r][col] = fmaxf(acc[c][r] + bf1[col], 0.f);
    }
  __syncthreads();
  {
    int nn = tid>>4, o = (tid>>3)&1, sub = tid&7;
    float s = 0.f;
#pragma unroll
    for (int k2=0;k2<32;k2++) s += hid[nn][k2*8 + sub] * Wf2[o*256 + k2*8 + sub];
    s += __shfl_xor(s, 1, 64);
    s += __shfl_xor(s, 2, 64);
    s += __shfl_xor(s, 4, 64);
    if (sub==0){
      s += bf2[o];
      out[((size_t)(n0+nn)*TSTEPS + t)*2 + o] = s;
      posL[nn][o] = s;
      xn[(size_t)(n0+nn)*XC0 + o] = (_Float16)s;
    }
  }
  __syncthreads();
  if (tid < 64){
    int nn = tid>>2, h = tid&3;
    float p0 = posL[nn][0], p1 = posL[nn][1];
    int sb = (n0+nn)*24 + h*6;
    float den = S[sb] + p0*S[sb+1] + p1*S[sb+2] + p0*p0*S[sb+3] + p0*p1*S[sb+4] + p1*p1*S[sb+5];
    denL[nn][h] = 1.0f/den;
  }
  __syncthreads();
#pragma unroll
  for (int half=0; half<2; half++){
    int hd = half*256 + tid;
    int h = hd>>7, d = hd&127;
    for (int nn=0; nn<16; nn++){
      float p0 = posL[nn][0], p1 = posL[nn][1];
      float fa = p0*p0, fb = p0*p1, fc = p1*p1;
      const float* mp = M + (size_t)((n0+nn)*24 + h*6)*128 + d;
      float num = mp[0] + p0*mp[128] + p1*mp[256] + fa*mp[384] + fb*mp[512] + fc*mp[640];
      xn[(size_t)(n0+nn)*XC0 + 36 + hd] = (_Float16)(num*denL[nn][h] + bv2[hd]);
    }
  }
}

// ======================= persistent kernel (R6) ===========================

struct LoopArgs {
  const _Float16* B0; const _Float16* B1;
  const float* b0; const float* b1;
  float* c0; float* c1;
  _Float16* x0; _Float16* x1; _Float16* h0; _Float16* h1;
  const _Float16* Wf1; const float* bf1; const float* Wf2; const float* bf2;
  const float* M; const float* S; const float* bv2;
  float* out; unsigned* bar;
};

// ---- barrier primitives ----
// FAST: same-XCD groups. stores write through L1 to the XCD L2; flag polls
// use sc0 (L1-bypass) loads -> L2-coherent, no MALL traffic, no invalidation.
// SLOW: agent-scope (MALL) protocol, verified in R5.

template<bool FAST>
__device__ __forceinline__ void arrive(unsigned* bar, int bid, unsigned val){
  __syncthreads();   // drains vmem of all waves before flag store
  if (threadIdx.x == 0){
    if (FAST)
      __hip_atomic_store(bar + (size_t)bid*FL, val, __ATOMIC_RELAXED,
                         __HIP_MEMORY_SCOPE_WORKGROUP);
    else
      __hip_atomic_store(bar + (size_t)bid*FL, val, __ATOMIC_RELEASE,
                         __HIP_MEMORY_SCOPE_AGENT);
  }
}

template<bool FAST>
__device__ __forceinline__ unsigned flagld(const unsigned* p){
  if (FAST){
    unsigned v;
    asm volatile("global_load_dword %0, %1, off sc0\n\ts_waitcnt vmcnt(0)"
                 : "=v"(v) : "v"(p) : "memory");
    return v;
  } else {
    return __hip_atomic_load(p, __ATOMIC_RELAXED, __HIP_MEMORY_SCOPE_AGENT);
  }
}

template<bool FAST>
__device__ __forceinline__ void wait32(unsigned* bar, int g, unsigned val){
  if (threadIdx.x < 64){
    int lane = threadIdx.x & 63;
    const unsigned* p = bar + (size_t)(g + 8*(lane & 31))*FL;
    for(;;){
      unsigned v = flagld<FAST>(p);
      if (__ballot(v >= val) == ~0ull) break;
      __builtin_amdgcn_s_sleep(1);
    }
  }
  __syncthreads();
}

template<bool FAST>
__device__ __forceinline__ void waitS3(unsigned* bar, int g, unsigned val){
  if (threadIdx.x < 64){
    int l5 = (threadIdx.x & 63) % 5;
    const unsigned* p = bar + (size_t)(g + 8*l5)*FL;
    for(;;){
      unsigned v = flagld<FAST>(p);
      if (__ballot(v >= val) == ~0ull) break;
      __builtin_amdgcn_s_sleep(1);
    }
  }
  __syncthreads();
}

// ---- pipelined K-chunk engine ----
// Block: 80 seqs x (16 cols x 4 gates).  8 waves = 4 gates x 2 K-halves.
// A superchunk = two 64-col chunks (one per K-half) staged to LDS; B frags
// are register-pinned.  2-deep asm pipeline: counted vmcnt(3), sched_barrier
// after each wait (rule #18), single barrier per superchunk.

#define KC_VW3 do{ if (FAST){ asm volatile("s_waitcnt vmcnt(3)":::"memory"); \
                   __builtin_amdgcn_sched_barrier(0);} }while(0)
#define KC_VW0 do{ if (FAST){ asm volatile("s_waitcnt vmcnt(0)":::"memory"); \
                   __builtin_amdgcn_sched_barrier(0);} }while(0)

#define KC_ISSUE(si, R) do{                                                   \
    const _Float16* p0 = saddr(si, 0);                                        \
    const _Float16* p1 = saddr(si, 1);                                        \
    const _Float16* p2 = saddr(si, 2);                                        \
    if (FAST){                                                                \
      asm volatile("global_load_dwordx4 %0, %3, off sc0\n\t"                  \
                   "global_load_dwordx4 %1, %4, off sc0\n\t"                  \
                   "global_load_dwordx4 %2, %5, off sc0"                      \
        : "=&v"((R)[0]), "=&v"((R)[1]), "=&v"((R)[2])                         \
        : "v"(p0), "v"(p1), "v"(p2) : "memory");                              \
    } else {                                                                  \
      (R)[0] = ldA(p0); (R)[1] = ldA(p1); (R)[2] = ldA(p2);                   \
    }                                                                         \
  }while(0)

#define KC_CONS(si) do{                                                       \
    _Float16* sb = ((si) & 1) ? sb1 : sb0;                                    \
    int cid = ks ? O[si] : E[si];                                             \
    if (!NEGO || cid >= 0){                                                   \
      _Pragma("unroll")                                                       \
      for (int st=0; st<5; ++st){                                             \
        int row = st*16 + lr;                                                 \
        hx8 af0 = *(const hx8*)(sb + row*128 + (((ks*8 + 0 + lq) ^ lr)<<3));  \
        acc[st] = __builtin_amdgcn_mfma_f32_16x16x32_f16(                     \
                      af0, pin[PB + (si)*2 + 0], acc[st], 0,0,0);             \
        hx8 af1 = *(const hx8*)(sb + row*128 + (((ks*8 + 4 + lq) ^ lr)<<3));  \
        acc[st] = __builtin_amdgcn_mfma_f32_16x16x32_f16(                     \
                      af1, pin[PB + (si)*2 + 1], acc[st], 0,0,0);             \
      }                                                                       \
    }                                                                         \
  }while(0)

#define KC_STEP(si)                                                           \
  if constexpr ((si) < NSC){                                                  \
    if constexpr ((si)+2 < NSC) KC_ISSUE((si)+2, (((si)&1)?RS1:RS0));         \
    if constexpr ((si)+1 < NSC){                                              \
      if constexpr ((si)+2 < NSC) KC_VW3; else KC_VW0;                        \
      swrite((si)+1, ((((si)+1)&1)?RS1:RS0), ((((si)+1)&1)?sb1:sb0));         \
    }                                                                         \
    KC_CONS(si);                                                              \
    if constexpr ((si)+1 < NSC) __syncthreads();                              \
  }

template<bool FAST, int NSC, int PB, bool NEGO, int NPIN>
__device__ __forceinline__ void kchunks(
    const _Float16* __restrict__ Ab, int lda, int seqbase,
    const int* __restrict__ E, const int* __restrict__ O,
    int tid, int ks, int lr, int lq,
    _Float16* __restrict__ sb0, _Float16* __restrict__ sb1,
    const hx8 (&pin)[NPIN], fx4 (&acc)[5])
{
  hx8 RS0[3], RS1[3];
  auto saddr = [&](int si, int j)->const _Float16* {
    int idx = j*512 + tid; if (idx > 1279) idx = 1279;
    int r = idx >> 4, sl = idx & 15;
    int cid = (sl < 8) ? E[si] : O[si];
    if (NEGO && cid < 0) cid = E[si];
    return Ab + (size_t)(seqbase + r)*lda + cid*64 + (sl&7)*8;
  };
  auto swrite = [&](int si, hx8* R, _Float16* sb){
#pragma unroll
    for (int j=0; j<3; ++j){
      int idx = j*512 + tid;
      if (idx < 1280){
        int r = idx >> 4, sl = idx & 15;
        if (!NEGO || sl < 8 || O[si] >= 0)
          *(hx8*)(sb + r*128 + ((sl ^ (r & 15)) << 3)) = R[j];
      }
    }
  };
  // prologue
  KC_ISSUE(0, RS0);
  KC_ISSUE(1, RS1);
  KC_VW3;
  swrite(0, RS0, sb0);
  __syncthreads();
  KC_STEP(0) KC_STEP(1) KC_STEP(2) KC_STEP(3) KC_STEP(4)
  KC_STEP(5) KC_STEP(6) KC_STEP(7) KC_STEP(8)
}

// eps exchange + fused LSTM epilogue.  eps[gate][seq 0..79][col 0..15].
__device__ __forceinline__ void gates_epilogue(
    float* __restrict__ epsL, fx4 (&acc)[5], int ks, int gw, int lr, int lq,
    int tid, const float* __restrict__ bias, float* __restrict__ cst,
    int c0, int seqbase,
    _Float16* __restrict__ h1p, int ldh1, int co1,
    _Float16* __restrict__ h2p, int ldh2, int co2)
{
  if (ks == 0){
#pragma unroll
    for (int st=0; st<5; ++st)
#pragma unroll
      for (int rr=0; rr<4; ++rr)
        epsL[(gw*80 + st*16 + lq*4 + rr)*16 + lr] = acc[st][rr];
  }
  __syncthreads();
  if (ks == 1){
#pragma unroll
    for (int st=0; st<5; ++st)
#pragma unroll
      for (int rr=0; rr<4; ++rr)
        epsL[(gw*80 + st*16 + lq*4 + rr)*16 + lr] += acc[st][rr];
  }
  __syncthreads();
#pragma unroll
  for (int e=0; e<3; ++e){
    int idx = e*512 + tid;
    if (idx < 1280){
      int ml = idx >> 4, j = idx & 15;
      float gi = epsL[(0*80+ml)*16+j] + bias[       c0+j];
      float gf = epsL[(1*80+ml)*16+j] + bias[ 512 + c0+j];
      float gg = epsL[(2*80+ml)*16+j] + bias[1024 + c0+j];
      float go = epsL[(3*80+ml)*16+j] + bias[1536 + c0+j];
      int ci = (seqbase+ml)*512 + c0 + j;
      float c_ = cst[ci];
      float cn = sigm(gf)*c_ + sigm(gi)*tanh_(gg);
      float hn = sigm(go)*tanh_(cn);
      cst[ci] = cn;
      _Float16 hh = (_Float16)hn;
      h1p[(size_t)(seqbase+ml)*ldh1 + co1 + c0 + j] = hh;
      if (h2p) h2p[(size_t)(seqbase+ml)*ldh2 + co2 + c0 + j] = hh;
    }
  }
}

// head + next-step attention: 512 threads, 16 seqs (n0..n0+16).
template<bool FAST>
__device__ __forceinline__ void s3_512(
    const _Float16* __restrict__ h1, int ldh,
    const _Float16* __restrict__ Wf1h, const float* __restrict__ bf1,
    const float* __restrict__ Wf2, const float* __restrict__ bf2,
    const float* __restrict__ M, const float* __restrict__ S,
    const float* __restrict__ bv2, _Float16* __restrict__ xn,
    float* __restrict__ out, int t, int n0, char* smem)
{
  float (*hid)[264] = (float(*)[264])smem;
  float (*posL)[2]  = (float(*)[2])(smem + 17024);
  float (*denL)[4]  = (float(*)[4])(smem + 17280);
  int tid = threadIdx.x, w = tid>>6, lane = tid&63, lr = lane&15, lq = lane>>4;
  fx4 acc0 = (fx4){0.f,0.f,0.f,0.f}, acc1 = (fx4){0.f,0.f,0.f,0.f};
  {
    const _Float16* ap  = h1 + (size_t)(n0+lr)*ldh + lq*8;
    const _Float16* bp0 = Wf1h + (size_t)(w*32 + lr)*512 + lq*8;
    const _Float16* bp1 = bp0 + 16*512;
#pragma unroll
    for (int kb=0; kb<4; ++kb){
      hx8 a0,a1,a2,a3;
      if (FAST){
        const _Float16* q0 = ap + (kb*4+0)*32;
        const _Float16* q1 = ap + (kb*4+1)*32;
        const _Float16* q2 = ap + (kb*4+2)*32;
        const _Float16* q3 = ap + (kb*4+3)*32;
        asm volatile("global_load_dwordx4 %0, %4, off sc0\n\t"
                     "global_load_dwordx4 %1, %5, off sc0\n\t"
                     "global_load_dwordx4 %2, %6, off sc0\n\t"
                     "global_load_dwordx4 %3, %7, off sc0\n\t"
                     "s_waitcnt vmcnt(0)"
          : "=&v"(a0), "=&v"(a1), "=&v"(a2), "=&v"(a3)
          : "v"(q0), "v"(q1), "v"(q2), "v"(q3) : "memory");
      } else {
        a0 = ldA(ap + (kb*4+0)*32); a1 = ldA(ap + (kb*4+1)*32);
        a2 = ldA(ap + (kb*4+2)*32); a3 = ldA(ap + (kb*4+3)*32);
      }
#pragma unroll
      for (int i=0;i<4;++i){
        hx8 a = (i==0)?a0:(i==1)?a1:(i==2)?a2:a3;
        int k = (kb*4+i)*32;
        acc0 = __builtin_amdgcn_mfma_f32_16x16x32_f16(a, *(const hx8*)(bp0+k), acc0, 0,0,0);
        acc1 = __builtin_amdgcn_mfma_f32_16x16x32_f16(a, *(const hx8*)(bp1+k), acc1, 0,0,0);
      }
    }
  }
#pragma unroll
  for (int r=0;r<4;++r){
    int row = lq*4+r;
    hid[row][w*32      + lr] = fmaxf(acc0[r] + bf1[w*32      + lr], 0.f);
    hid[row][w*32 + 16 + lr] = fmaxf(acc1[r] + bf1[w*32 + 16 + lr], 0.f);
  }
  __syncthreads();
  {
    int nn = tid>>5, o = (tid>>4)&1, sub = tid&15;
    float s = 0.f;
#pragma unroll
    for (int k2=0;k2<16;++k2) s += hid[nn][k2*16 + sub] * Wf2[o*256 + k2*16 + sub];
    s += __shfl_xor(s, 1, 64);
    s += __shfl_xor(s, 2, 64);
    s += __shfl_xor(s, 4, 64);
    s += __shfl_xor(s, 8, 64);
    if (sub==0){
      s += bf2[o];
      out[((size_t)(n0+nn)*TSTEPS + t)*2 + o] = s;
      posL[nn][o] = s;
      xn[(size_t)(n0+nn)*XC0 + o] = (_Float16)s;
    }
  }
  __syncthreads();
  if (tid < 64){
    int nn = tid>>2, h = tid&3;
    float p0 = posL[nn][0], p1 = posL[nn][1];
    int sb = (n0+nn)*24 + h*6;
    float den = S[sb] + p0*S[sb+1] + p1*S[sb+2] + p0*p0*S[sb+3] + p0*p1*S[sb+4] + p1*p1*S[sb+5];
    denL[nn][h] = 1.0f/den;
  }
  __syncthreads();
  {
    int hd = tid, h = hd>>7, d = hd&127;
    for (int nn=0; nn<16; ++nn){
      float p0 = posL[nn][0], p1 = posL[nn][1];
      float fa = p0*p0, fb = p0*p1, fc = p1*p1;
      const float* mp = M + (size_t)((n0+nn)*24 + h*6)*128 + d;
      float num = mp[0] + p0*mp[128] + p1*mp[256] + fa*mp[384] + fb*mp[512] + fc*mp[640];
      xn[(size_t)(n0+nn)*XC0 + 36 + hd] = (_Float16)(num*denL[nn][h] + bv2[hd]);
    }
  }
}

template<bool FAST>
__device__ __forceinline__ void run_loop(const LoopArgs& a, char* smem, int bid){
  constexpr int E0A[4] = {16,10,12,14}; constexpr int O0A[4] = {9,11,13,15};
  constexpr int E0B[5] = {0,2,4,6,8};   constexpr int O0B[5] = {1,3,5,7,-1};
  constexpr int E1[8]  = {0,2,4,6,8,10,12,14};
  constexpr int O1[8]  = {1,3,5,7,9,11,13,15};
  int tid = threadIdx.x;
  int g = bid & 7, rank = bid >> 3;
  int wid = tid >> 6, lane = tid & 63, lr = lane & 15, lq = lane >> 4;
  int gw = wid & 3, ks = wid >> 2;
  int c0 = rank * 16, seqbase = g * 80;
  _Float16* sb0 = (_Float16*)smem;
  _Float16* sb1 = (_Float16*)(smem + 20480);
  float* epsL = (float*)(smem + 40960);

  // ---- pin B fragments in registers (one-time; statically indexed) ----
  hx8 pinB0[18]; hx8 pinB1[16];
  {
    const _Float16* b0r = a.B0 + (size_t)(gw*512 + c0 + lr)*XC0 + lq*8;
    const _Float16* b1r = a.B1 + (size_t)(gw*512 + c0 + lr)*XC1 + lq*8;
#define PINL0(si, base, TE, TO)                                               \
    { int cid = ks ? TO[si] : TE[si];                                         \
      if (cid >= 0){                                                          \
        pinB0[(base)+(si)*2+0] = *(const hx8*)(b0r + cid*64);                 \
        pinB0[(base)+(si)*2+1] = *(const hx8*)(b0r + cid*64 + 32);            \
      } }
    PINL0(0,0,E0A,O0A) PINL0(1,0,E0A,O0A) PINL0(2,0,E0A,O0A) PINL0(3,0,E0A,O0A)
    PINL0(0,8,E0B,O0B) PINL0(1,8,E0B,O0B) PINL0(2,8,E0B,O0B) PINL0(3,8,E0B,O0B)
    PINL0(4,8,E0B,O0B)
#undef PINL0
#define PINL1(si)                                                             \
    { int cid = ks ? O1[si] : E1[si];                                         \
      pinB1[(si)*2+0] = *(const hx8*)(b1r + cid*64);                          \
      pinB1[(si)*2+1] = *(const hx8*)(b1r + cid*64 + 32); }
    PINL1(0) PINL1(1) PINL1(2) PINL1(3) PINL1(4) PINL1(5) PINL1(6) PINL1(7)
#undef PINL1
  }

  for (int t = 0; t < TSTEPS; ++t){
    unsigned bb = 16u + (unsigned)t*3u;
    _Float16* xin = (t&1) ? a.x1 : a.x0;
    _Float16* xnx = (t&1) ? a.x0 : a.x1;
    _Float16* hin = (t&1) ? a.h1 : a.h0;
    _Float16* hnx = (t&1) ? a.h0 : a.h1;
    fx4 acc[5];
#pragma unroll
    for (int i=0;i<5;++i) acc[i] = (fx4){0.f,0.f,0.f,0.f};
    // layer 0, h0-half (chunks 9..16): ready since prev flag1
    kchunks<FAST,4,0,false,18>(xin, XC0, seqbase, E0A, O0A,
                               tid, ks, lr, lq, sb0, sb1, pinB0, acc);
    // x-half needs s3(t-1) (flags init to 16 => t=0 passes trivially)
    waitS3<FAST>(a.bar, g, bb);
    kchunks<FAST,5,8,true,18>(xin, XC0, seqbase, E0B, O0B,
                              tid, ks, lr, lq, sb0, sb1, pinB0, acc);
    gates_epilogue(epsL, acc, ks, gw, lr, lq, tid, a.b0, a.c0, c0, seqbase,
                   hin, XC1, 0, xnx, XC0, 576);
    arrive<FAST>(a.bar, bid, bb+1);
    wait32<FAST>(a.bar, g, bb+1);
    // layer 1
#pragma unroll
    for (int i=0;i<5;++i) acc[i] = (fx4){0.f,0.f,0.f,0.f};
    kchunks<FAST,8,0,false,16>(hin, XC1, seqbase, E1, O1,
                               tid, ks, lr, lq, sb0, sb1, pinB1, acc);
    gates_epilogue(epsL, acc, ks, gw, lr, lq, tid, a.b1, a.c1, c0, seqbase,
                   hnx, XC1, 512, (_Float16*)0, 0, 0);
    arrive<FAST>(a.bar, bid, bb+2);
    // head + attention: ranks 0..4 handle 16 seqs each
    if (rank < 5){
      wait32<FAST>(a.bar, g, bb+2);
      s3_512<FAST>(hnx + 512, XC1, a.Wf1, a.bf1, a.Wf2, a.bf2, a.M, a.S,
                   a.bv2, xnx, a.out, t, seqbase + rank*16, smem);
      arrive<FAST>(a.bar, bid, bb+3);
    }
  }
}

__global__ __launch_bounds__(512, 2) void kloop(LoopArgs a){
  __shared__ __align__(16) char smem[61440];
  int bid = blockIdx.x, tid = threadIdx.x;
  unsigned* pub = a.bar + PUB;
  // publish this block's physical XCD id
  if (tid == 0){
    unsigned xcc;
    asm volatile("s_getreg_b32 %0, hwreg(20, 0, 32)" : "=s"(xcc));
    __hip_atomic_store(pub + bid, (xcc & 255u) + 1u, __ATOMIC_RELAXED,
                       __HIP_MEMORY_SCOPE_AGENT);
  }
  // block 0: verdict = 1 (fast) iff every group (bid&7) is XCD-uniform and
  // the 8 group ids are a permutation of 0..7 (guards bogus getreg too).
  if (bid == 0){
    unsigned* xs = (unsigned*)smem;
    if (tid < 256){
      unsigned v;
      do { v = __hip_atomic_load(pub + tid, __ATOMIC_RELAXED,
                                 __HIP_MEMORY_SCOPE_AGENT); } while (!v);
      xs[tid] = v;
    }
    __syncthreads();
    if (tid == 0){
      int ok = 1; unsigned mask = 0;
      for (int g2 = 0; g2 < 8; ++g2){
        unsigned v0 = xs[g2];
        if (v0 - 1u > 7u) ok = 0; else mask |= 1u << (v0 - 1u);
        for (int r2 = 1; r2 < 32; ++r2) if (xs[g2 + 8*r2] != v0) ok = 0;
      }
      if (mask != 0xFFu) ok = 0;
      __hip_atomic_store(pub + 256, ok ? 1u : 2u, __ATOMIC_RELAXED,
                         __HIP_MEMORY_SCOPE_AGENT);
    }
    __syncthreads();
  }
  __shared__ unsigned sv;
  if (tid == 0){
    unsigned v;
    do { v = __hip_atomic_load(pub + 256, __ATOMIC_RELAXED,
                               __HIP_MEMORY_SCOPE_AGENT); } while (!v);
    sv = v;
  }
  __syncthreads();
  if (sv == 1u) run_loop<true>(a, smem, bid);
  else          run_loop<false>(a, smem, bid);
}

// ---------------------------------------------------------------------------

extern "C" void kernel_launch(void* const* d_in, const int* in_sizes, int n_in,
                              void* d_out, int out_size, void* d_ws, size_t ws_size,
                              hipStream_t stream) {
  const float* ctx   = (const float*)d_in[0];
  const float* ipos  = (const float*)d_in[1];
  const float* ball  = (const float*)d_in[2];
  const int*   roles = (const int*)  d_in[3];
  const float* remb  = (const float*)d_in[5];
  const float* Wc    = (const float*)d_in[6];
  const float* bc    = (const float*)d_in[7];
  const float* Wq    = (const float*)d_in[8];
  const float* bq    = (const float*)d_in[9];
  const float* Wk    = (const float*)d_in[10];
  const float* bk    = (const float*)d_in[11];
  const float* Wv    = (const float*)d_in[12];
  const float* bv    = (const float*)d_in[13];
  const float* Wo    = (const float*)d_in[14];
  const float* bo    = (const float*)d_in[15];
  const float* Wih0  = (const float*)d_in[16];
  const float* Whh0  = (const float*)d_in[17];
  const float* bih0  = (const float*)d_in[18];
  const float* bhh0  = (const float*)d_in[19];
  const float* Wih1  = (const float*)d_in[20];
  const float* Whh1  = (const float*)d_in[21];
  const float* bih1  = (const float*)d_in[22];
  const float* bhh1  = (const float*)d_in[23];
  const float* Wf1   = (const float*)d_in[24];
  const float* bf1   = (const float*)d_in[25];
  const float* Wf2   = (const float*)d_in[26];
  const float* bf2   = (const float*)d_in[27];
  float* out = (float*)d_out;

  char* w = (char*)d_ws;
  auto alloc = [&](size_t bytes){ void* p = (void*)w; w += (bytes + 255) & ~(size_t)255; return p; };
  float* fY    = (float*)alloc(12*512*4);
  float* fcc   = (float*)alloc(12*4);
  float* fu    = (float*)alloc(3*512*4);
  float* fz    = (float*)alloc(12*512*4);
  float* fbv2  = (float*)alloc(512*4);
  float* fWcv  = (float*)alloc((size_t)512*512*4);
  float* fWcvT = (float*)alloc((size_t)512*512*4);
  float* fWmix = (float*)alloc((size_t)2048*512*4);
  _Float16* hB0  = (_Float16*)alloc((size_t)2048*XC0*2);
  _Float16* hB1  = (_Float16*)alloc((size_t)2048*XC1*2);
  _Float16* hWf1 = (_Float16*)alloc((size_t)256*512*2);
  float* fb0 = (float*)alloc(2048*4);
  float* fb1 = (float*)alloc(2048*4);
  float* fW6 = (float*)alloc((size_t)NSEQ*24*200*4);
  float* fS  = (float*)alloc((size_t)NSEQ*24*4);
  float* fF  = (float*)alloc((size_t)NSEQ*24*512*4);
  float* fM  = (float*)alloc((size_t)NSEQ*24*128*4);
  _Float16* xc0 = (_Float16*)alloc((size_t)NSEQ*XC0*2);
  _Float16* xc1 = (_Float16*)alloc((size_t)NSEQ*XC0*2);
  _Float16* hc0 = (_Float16*)alloc((size_t)NSEQ*XC1*2);
  _Float16* hc1 = (_Float16*)alloc((size_t)NSEQ*XC1*2);
  float* fc0 = (float*)alloc((size_t)NSEQ*512*4);
  float* fc1 = (float*)alloc((size_t)NSEQ*512*4);
  unsigned* bar = (unsigned*)alloc((size_t)(PUB + 640)*4);

  // ---- folds ----
  kF1 <<<2,  256, 0, stream>>>(Wq, Wc, bc, bq, fu);
  kF2a<<<12, 512, 0, stream>>>(Wk, fu, fz);
  kF2b<<<12, 512, 0, stream>>>(fz, Wc, bc, bk, fu, fY, fcc);
  kFbv<<<2,  256, 0, stream>>>(Wv, bc, bv, fbv2);
  kgemm<<<dim3(8,8),  256, 0, stream>>>(Wv,   512, 0,  Wc, 512, fWcv,  512, 512);
  ktransp<<<1024, 256, 0, stream>>>(fWcv, fWcvT);
  kgemm<<<dim3(8,32), 256, 0, stream>>>(Wih0, 548, 36, Wo, 512, fWmix, 512, 512);
  kbcat0<<<2048, 256, 0, stream>>>(Wih0, fWmix, Whh0, hB0);
  kbcat1<<<2048, 256, 0, stream>>>(Wih1, Whh1, hB1);
  kcast<<<512,  256, 0, stream>>>(Wf1, hWf1, 256*512);
  kbias<<<8, 256, 0, stream>>>(Wih0, bo, bih0, bhh0, bih1, bhh1, fb0, fb1);

  // ---- moments ----
  kP1<<<NSEQ, 256, 0, stream>>>(ctx, fY, fcc, fW6);
  kP2<<<NSEQ, 256, 0, stream>>>(ctx, fW6, fF, fS);
  kP3<<<NSEQ*4, 128, 0, stream>>>(fF, fWcvT, fM);

  // ---- state init ----
  kinit<<<NSEQ, 512, 0, stream>>>(ball, roles, remb, xc0, xc1, hc0, hc1, fc0, fc1, bar);
  katt0<<<NSEQ, 128, 0, stream>>>(ipos, fM, fS, fbv2, xc0);

  // ---- recurrent loop ----
  int maxb = 0;
  hipError_t qe = hipOccupancyMaxActiveBlocksPerMultiprocessor(
      &maxb, reinterpret_cast<const void*>(kloop), 512, 0);
  if (qe == hipSuccess && maxb >= 1){
    LoopArgs la;
    la.B0 = hB0; la.B1 = hB1; la.b0 = fb0; la.b1 = fb1;
    la.c0 = fc0; la.c1 = fc1;
    la.x0 = xc0; la.x1 = xc1; la.h0 = hc0; la.h1 = hc1;
    la.Wf1 = hWf1; la.bf1 = bf1; la.Wf2 = Wf2; la.bf2 = bf2;
    la.M = fM; la.S = fS; la.bv2 = fbv2; la.out = out; la.bar = bar;
    kloop<<<NBLK, 512, 0, stream>>>(la);
  } else {
    for (int t = 0; t < TSTEPS; ++t){
      _Float16* xin  = (t&1) ? xc1 : xc0;
      _Float16* xnx  = (t&1) ? xc0 : xc1;
      _Float16* hin  = (t&1) ? hc1 : hc0;
      _Float16* hnx  = (t&1) ? hc0 : hc1;
      kgates<17><<<640, 256, 0, stream>>>(xin, XC0, hB0, fb0, fc0,
                                          hin, XC1, 0, xnx, XC0, 576);
      kgates<16><<<640, 256, 0, stream>>>(hin, XC1, hB1, fb1, fc1,
                                          hnx, XC1, 512, (_Float16*)nullptr, 0, 0);
      ks3b<<<40, 256, 0, stream>>>(hnx + 512, XC1, hWf1, bf1, Wf2, bf2,
                                   fM, fS, fbv2, xnx, out, t);
    }
  }
}

// Round 5
// 4548.177 us; speedup vs baseline: 1.1339x; 1.1339x over previous
//
#include <hip/hip_runtime.h>
#include <hip/hip_bf16.h>
#include <cstddef>

// ---------------------------------------------------------------------------
// AttentionLSTMDecoder on MI355X.  Round 7.
//  * R1-2: K/V folded to pos-affine scores, exp Taylor -> V-moment ratio;
//    Wo folded into W_ih0; one K=1088/1024 GEMM per layer per step.
//  * R3: persistent kernel.  R4 (best, 4810us): LDS XOR swizzle + global
//    flag barrier, cached loads + acquire-inv coherence.  R5/R6: group/XCD
//    sync experiments -- no net win (R6 likely fell back to slow path).
//  * R7 (this): R4 data path EXACTLY (cached loads, release/acquire agent
//    coherence) + group-local 32-block barriers (one release-store arrival,
//    64-lane ballot poll, single acquire on success) + deferred s3 wait
//    (h0-half chunks run before the 2-flag s3 wait) + depth-3 staging
//    prefetch.  No XCD assumptions anywhere.
// ---------------------------------------------------------------------------

typedef _Float16 hx8 __attribute__((ext_vector_type(8)));
typedef float fx4 __attribute__((ext_vector_type(4)));

#define NSEQ 640
#define TSTEPS 100
#define XC0 1088   // [x(576) | h0(512)]
#define XC1 1024   // [h0(512) | h1(512)]
#define NBLK 640   // persistent grid
#define FL 32      // u32 stride per flag line (128B)

__device__ __forceinline__ float sigm(float x){ return 1.0f/(1.0f+__expf(-x)); }
__device__ __forceinline__ float tanh_(float x){
  x = fminf(fmaxf(x, -15.0f), 15.0f);
  float e = __expf(2.0f*x);
  return (e-1.0f)/(e+1.0f);
}
__device__ __forceinline__ float sel4(float a0,float a1,float a2,float a3,int h){
  float r = a0; r = (h==1)?a1:r; r = (h==2)?a2:r; r = (h==3)?a3:r; return r;
}

// ---------------- fold kernels (one-time) ----------------

__global__ void kF1(const float* __restrict__ Wq, const float* __restrict__ Wc,
                    const float* __restrict__ bc, const float* __restrict__ bq,
                    float* __restrict__ u){
  int r = blockIdx.x*256 + threadIdx.x; if (r >= 512) return;
  float s0=0.f, s1=0.f, s2=0.f;
  for (int k=0;k<512;k++){
    float wq = Wq[r*512+k];
    s0 += wq*Wc[k*512+0];
    s1 += wq*Wc[k*512+1];
    s2 += wq*bc[k];
  }
  u[r]=s0; u[512+r]=s1; u[1024+r]=s2+bq[r];
}

__global__ __launch_bounds__(512) void kF2a(const float* __restrict__ Wk,
                                            const float* __restrict__ u,
                                            float* __restrict__ z){
  int ih = blockIdx.x; int kk = threadIdx.x;
  int i = ih>>2, h = ih&3;
  float s = 0.f;
  for (int d=0; d<128; d++)
    s += Wk[(h*128+d)*512 + kk] * u[i*512 + h*128 + d];
  z[ih*512+kk] = s;
}

__global__ __launch_bounds__(512) void kF2b(const float* __restrict__ z,
                                            const float* __restrict__ Wc,
                                            const float* __restrict__ bc,
                                            const float* __restrict__ bk,
                                            const float* __restrict__ u,
                                            float* __restrict__ Y, float* __restrict__ cc){
  const float scale = 0.08838834764831845f; // 1/sqrt(128)
  int ih = blockIdx.x; int j = threadIdx.x;
  int i = ih>>2, h = ih&3;
  float s = 0.f;
  for (int kk=0;kk<512;kk++) s += z[ih*512+kk]*Wc[kk*512+j];
  Y[ih*512+j] = s*scale;
  if (j==0){
    float t=0.f;
    for (int kk=0;kk<512;kk++) t += z[ih*512+kk]*bc[kk];
    for (int d=0;d<128;d++) t += u[i*512+h*128+d]*bk[h*128+d];
    cc[ih] = t*scale;
  }
}

__global__ void kFbv(const float* __restrict__ Wv, const float* __restrict__ bc,
                     const float* __restrict__ bv, float* __restrict__ bv2){
  int r = blockIdx.x*256 + threadIdx.x; if (r >= 512) return;
  float s = bv[r];
  for (int k=0;k<512;k++) s += Wv[r*512+k]*bc[k];
  bv2[r]=s;
}

// fp32 tiled GEMM: C[M,N] = A[:, aoff:aoff+K] @ B (64x64 tiles)
__global__ __launch_bounds__(256) void kgemm(const float* __restrict__ A, int lda, int aoff,
                                             const float* __restrict__ B, int ldb,
                                             float* __restrict__ C, int ldc, int K){
  __shared__ float As[64][16];
  __shared__ float Bs[16][64];
  int tid = threadIdx.x; int tx = tid&15, ty = tid>>4;
  int bx = blockIdx.x, by = blockIdx.y;
  float acc[4][4];
#pragma unroll
  for (int i=0;i<4;i++)
#pragma unroll
    for (int j=0;j<4;j++) acc[i][j]=0.f;
  for (int kk=0; kk<K; kk+=16){
#pragma unroll
    for (int e=0;e<4;e++){
      int id = tid*4+e;
      int r = id>>4, c = id&15;
      As[r][c] = A[(size_t)(by*64+r)*lda + aoff + kk + c];
      int r2 = id>>6, c2 = id&63;
      Bs[r2][c2] = B[(size_t)(kk+r2)*ldb + bx*64 + c2];
    }
    __syncthreads();
#pragma unroll
    for (int k=0;k<16;k++){
      float bvv[4];
#pragma unroll
      for (int j=0;j<4;j++) bvv[j] = Bs[k][tx*4+j];
#pragma unroll
      for (int i=0;i<4;i++){
        float av = As[ty*4+i][k];
#pragma unroll
        for (int j=0;j<4;j++) acc[i][j] += av*bvv[j];
      }
    }
    __syncthreads();
  }
#pragma unroll
  for (int i=0;i<4;i++)
#pragma unroll
    for (int j=0;j<4;j++)
      C[(size_t)(by*64+ty*4+i)*ldc + bx*64+tx*4+j] = acc[i][j];
}

__global__ void ktransp(const float* __restrict__ A, float* __restrict__ AT){
  int idx = blockIdx.x*256 + threadIdx.x;
  int r = idx>>9, c = idx&511;
  AT[c*512 + r] = A[idx];
}

// Bcat0 [2048][1088] = [Wih0[:,0:36] | Wmix | 0pad(28) | Whh0]
__global__ void kbcat0(const float* __restrict__ Wih0, const float* __restrict__ Wmix,
                       const float* __restrict__ Whh0, _Float16* __restrict__ B){
  int r = blockIdx.x;
  for (int c = threadIdx.x; c < 1088; c += 256){
    float v;
    if (c < 36) v = Wih0[r*548 + c];
    else if (c < 548) v = Wmix[r*512 + (c-36)];
    else if (c < 576) v = 0.f;
    else v = Whh0[r*512 + (c-576)];
    B[(size_t)r*1088 + c] = (_Float16)v;
  }
}

// Bcat1 [2048][1024] = [Wih1 | Whh1]
__global__ void kbcat1(const float* __restrict__ Wih1, const float* __restrict__ Whh1,
                       _Float16* __restrict__ B){
  int r = blockIdx.x;
  for (int c = threadIdx.x; c < 1024; c += 256){
    float v = (c < 512) ? Wih1[r*512 + c] : Whh1[r*512 + (c-512)];
    B[(size_t)r*1024 + c] = (_Float16)v;
  }
}

__global__ void kcast(const float* __restrict__ s, _Float16* __restrict__ d, int n){
  int i = blockIdx.x*256 + threadIdx.x;
  if (i < n) d[i] = (_Float16)s[i];
}

// b0 = bih0+bhh0+Wih0[:,36:]@bo ; b1 = bih1+bhh1
__global__ void kbias(const float* __restrict__ Wih0, const float* __restrict__ bo,
                      const float* __restrict__ bih0, const float* __restrict__ bhh0,
                      const float* __restrict__ bih1, const float* __restrict__ bhh1,
                      float* __restrict__ b0, float* __restrict__ b1){
  int j = blockIdx.x*256 + threadIdx.x; if (j >= 2048) return;
  float s = bih0[j]+bhh0[j];
  for (int k=0;k<512;k++) s += Wih0[j*548+36+k]*bo[k];
  b0[j]=s; b1[j]=bih1[j]+bhh1[j];
}

// ---------------- moment precompute ----------------

__global__ __launch_bounds__(256) void kP1(const float* __restrict__ ctx,
                                           const float* __restrict__ Y,
                                           const float* __restrict__ cc,
                                           float* __restrict__ W6){
  __shared__ float Yl[6144];
  __shared__ float ccl[12];
  int tid = threadIdx.x; int n = blockIdx.x;
  for (int e = tid; e < 6144; e += 256) Yl[e] = Y[e];
  if (tid < 12) ccl[tid] = cc[tid];
  __syncthreads();
  int wave = tid >> 6, lane = tid & 63;
  for (int it = 0; it < 50; ++it){
    int s = it*4 + wave;
    const float* cp = ctx + ((size_t)n*200 + s)*512;
    float p[12];
#pragma unroll
    for (int i=0;i<12;i++) p[i]=0.f;
    for (int c8 = 0; c8 < 8; ++c8){
      int col = c8*64 + lane;
      float v = cp[col];
#pragma unroll
      for (int i=0;i<12;i++) p[i] += v * Yl[i*512+col];
    }
#pragma unroll
    for (int m = 32; m; m >>= 1){
#pragma unroll
      for (int i=0;i<12;i++) p[i] += __shfl_xor(p[i], m, 64);
    }
    if (lane < 4){
      int h = lane;
      float a  = sel4(p[0],p[1],p[2], p[3], h) + ccl[h];
      float b  = sel4(p[4],p[5],p[6], p[7], h) + ccl[4+h];
      float cp_= sel4(p[8],p[9],p[10],p[11],h) + ccl[8+h];
      float beta = __expf(cp_);
      size_t base = (size_t)(n*24 + h*6)*200 + s;
      W6[base + 0*200] = beta;
      W6[base + 1*200] = beta*a;
      W6[base + 2*200] = beta*b;
      W6[base + 3*200] = beta*a*a*0.5f;
      W6[base + 4*200] = beta*a*b;
      W6[base + 5*200] = beta*b*b*0.5f;
    }
  }
}

__global__ __launch_bounds__(256) void kP2(const float* __restrict__ ctx,
                                           const float* __restrict__ W6,
                                           float* __restrict__ F, float* __restrict__ S){
  __shared__ float w6[4800];
  int tid = threadIdx.x, n = blockIdx.x;
  for (int e = tid; e < 4800; e += 256) w6[e] = W6[(size_t)n*4800 + e];
  __syncthreads();
  float a0[24], a1[24];
#pragma unroll
  for (int r=0;r<24;r++){ a0[r]=0.f; a1[r]=0.f; }
  const float* cp = ctx + (size_t)n*200*512;
  for (int s=0;s<200;s++){
    float v0 = cp[s*512 + tid];
    float v1 = cp[s*512 + tid + 256];
#pragma unroll
    for (int r=0;r<24;r++){ float w = w6[r*200+s]; a0[r]+=w*v0; a1[r]+=w*v1; }
  }
#pragma unroll
  for (int r=0;r<24;r++){
    F[(size_t)(n*24+r)*512 + tid]       = a0[r];
    F[(size_t)(n*24+r)*512 + tid + 256] = a1[r];
  }
  if (tid < 24){
    float s=0.f;
    for (int ss=0; ss<200; ss++) s += w6[tid*200+ss];
    S[n*24+tid]=s;
  }
}

__global__ __launch_bounds__(128) void kP3(const float* __restrict__ F,
                                           const float* __restrict__ WcvT,
                                           float* __restrict__ M){
  __shared__ float Fl[3072];
  int tid = threadIdx.x; int b = blockIdx.x; int n = b>>2, h = b&3;
  for (int e = tid; e < 3072; e += 128) Fl[e] = F[(size_t)(n*24 + h*6)*512 + e];
  __syncthreads();
  float acc[6];
#pragma unroll
  for (int i=0;i<6;i++) acc[i]=0.f;
  for (int k=0;k<512;k++){
    float w = WcvT[k*512 + h*128 + tid];
#pragma unroll
    for (int i=0;i<6;i++) acc[i] += w * Fl[i*512+k];
  }
#pragma unroll
  for (int i=0;i<6;i++) M[(size_t)(n*24+h*6+i)*128 + tid] = acc[i];
}

// ---------------- state init ----------------

// fills xcat const regions, zeros h/c state, zeros flag lines:
// L0f = bar[bid], L1f = bar[640+bid], s3f = bar[1280+i] (i<40); stride FL.
__global__ __launch_bounds__(512) void kinit(const float* __restrict__ ball,
                    const int* __restrict__ roles, const float* __restrict__ remb,
                    _Float16* __restrict__ x0, _Float16* __restrict__ x1,
                    _Float16* __restrict__ hc0, _Float16* __restrict__ hc1,
                    float* __restrict__ c0, float* __restrict__ c1,
                    unsigned* __restrict__ bar){
  int n = blockIdx.x, tid = threadIdx.x;
  int b = n/10;
  int role = roles[n];
  for (int c = tid; c < XC0; c += 512){
    float v = 0.f;
    if (c>=2 && c<4)       v = ball[b*2 + (c-2)];
    else if (c>=4 && c<36) v = remb[role*32 + (c-4)];
    _Float16 hv = (_Float16)v;
    x0[(size_t)n*XC0+c] = hv;
    x1[(size_t)n*XC0+c] = hv;
  }
  for (int c = tid; c < XC1; c += 512){
    hc0[(size_t)n*XC1+c] = (_Float16)0.f;
    hc1[(size_t)n*XC1+c] = (_Float16)0.f;
  }
  if (tid < 512){
    c0[n*512+tid]=0.f; c1[n*512+tid]=0.f;
  }
  if (tid < FL){
    bar[(size_t)n*FL + tid] = 0u;
    bar[(size_t)(640+n)*FL + tid] = 0u;
    if (n < 40) bar[(size_t)(1280+n)*FL + tid] = 0u;
  }
}

// attention (Taylor-moment) for t=0 into xcat buf0
__global__ __launch_bounds__(128) void katt0(const float* __restrict__ ipos,
                                             const float* __restrict__ M,
                                             const float* __restrict__ S,
                                             const float* __restrict__ bv2,
                                             _Float16* __restrict__ x){
  int n = blockIdx.x, tid = threadIdx.x;
  float p0 = ipos[n*2], p1 = ipos[n*2+1];
  if (tid==0){ x[(size_t)n*XC0]=(_Float16)p0; x[(size_t)n*XC0+1]=(_Float16)p1; }
  float fa=p0*p0, fb=p0*p1, fc=p1*p1;
  for (int hd = tid; hd < 512; hd += 128){
    int h = hd>>7;
    int sb = n*24 + h*6;
    float den = S[sb] + p0*S[sb+1] + p1*S[sb+2] + fa*S[sb+3] + fb*S[sb+4] + fc*S[sb+5];
    const float* mp = M + (size_t)sb*128 + (hd&127);
    float num = mp[0] + p0*mp[128] + p1*mp[256] + fa*mp[384] + fb*mp[512] + fc*mp[640];
    x[(size_t)n*XC0 + 36 + hd] = (_Float16)(num/den + bv2[hd]);
  }
}

// ---------------- GEMM core + epilogue (R4 data path) ----------------

// Accumulating K-chunk core.  Block task = (mblk, jb): 32 seqs x 16 cols x
// 4 gates.  4 waves, 1 gate each.  LDS double-buffered K=64 chunks,
// XOR-swizzled (slot ^= row&7) writes AND reads.  Cached loads, depth-3
// register prefetch.  ord[] = chunk column ids (constant-folded).
template<int NCH>
__device__ __forceinline__ void gates_core(
    const _Float16* __restrict__ A, int lda,
    const _Float16* __restrict__ B, int ldb,
    const int (&ord)[NCH], int m0, int j0,
    _Float16* __restrict__ sbase, fx4& ac0, fx4& ac1)
{
  int tid = threadIdx.x, w = tid>>6, lane = tid&63;
  int lr = lane&15, lq = lane>>4;
  int li = lane>>3, lc = lane&7;
  const _Float16* gA  = A + (size_t)(m0 + w*8 + li)*lda + lc*8;
  const _Float16* gB0 = B + (size_t)(w*512 + j0 + li)*ldb + lc*8;
  const _Float16* gB1 = B + (size_t)(w*512 + j0 + 8 + li)*ldb + lc*8;
  int sA  = (w*8 + li)*64         + ((lc ^ li)<<3);
  int sB0 = 2048 + (w*16 + li)*64 + ((lc ^ li)<<3);
  int sB1 = 2048 + (w*16 + 8 + li)*64 + ((lc ^ li)<<3);
  int ra7 = lr & 7;
  int fA00 = lr*64        + (((lq  ) ^ ra7)<<3);
  int fA01 = lr*64        + (((lq+4) ^ ra7)<<3);
  int fA10 = (16+lr)*64   + (((lq  ) ^ ra7)<<3);
  int fA11 = (16+lr)*64   + (((lq+4) ^ ra7)<<3);
  int fB0  = 2048 + (w*16+lr)*64 + (((lq  ) ^ ra7)<<3);
  int fB1  = 2048 + (w*16+lr)*64 + (((lq+4) ^ ra7)<<3);
  hx8 pA[3], pB0[3], pB1[3];
#pragma unroll
  for (int i=0;i<3;i++){
    if (i < NCH){
      int k = ord[i]*64;
      pA[i]  = *(const hx8*)(gA  + k);
      pB0[i] = *(const hx8*)(gB0 + k);
      pB1[i] = *(const hx8*)(gB1 + k);
    }
  }
#pragma unroll
  for (int c=0; c<NCH; ++c){
    const int s = c % 3;
    _Float16* sb = sbase + (c&1)*6144;
    *(hx8*)(sb + sA)  = pA[s];
    *(hx8*)(sb + sB0) = pB0[s];
    *(hx8*)(sb + sB1) = pB1[s];
    __syncthreads();
    if (c+3 < NCH){
      int k = ord[c+3]*64;
      pA[s]  = *(const hx8*)(gA  + k);
      pB0[s] = *(const hx8*)(gB0 + k);
      pB1[s] = *(const hx8*)(gB1 + k);
    }
    hx8 b0 = *(const hx8*)(sb + fB0);
    hx8 a0 = *(const hx8*)(sb + fA00);
    hx8 a1 = *(const hx8*)(sb + fA10);
    ac0 = __builtin_amdgcn_mfma_f32_16x16x32_f16(a0, b0, ac0, 0,0,0);
    ac1 = __builtin_amdgcn_mfma_f32_16x16x32_f16(a1, b0, ac1, 0,0,0);
    hx8 b1  = *(const hx8*)(sb + fB1);
    hx8 a0b = *(const hx8*)(sb + fA01);
    hx8 a1b = *(const hx8*)(sb + fA11);
    ac0 = __builtin_amdgcn_mfma_f32_16x16x32_f16(a0b, b1, ac0, 0,0,0);
    ac1 = __builtin_amdgcn_mfma_f32_16x16x32_f16(a1b, b1, ac1, 0,0,0);
  }
}

// eps exchange + fused LSTM (R4 verbatim)
__device__ __forceinline__ void gates_epi(
    float (*eps)[32][16], fx4& ac0, fx4& ac1, int m0, int j0,
    const float* __restrict__ bias, float* __restrict__ cst,
    _Float16* __restrict__ h1p, int ldh1, int co1,
    _Float16* __restrict__ h2p, int ldh2, int co2)
{
  int tid = threadIdx.x, w = tid>>6, lane = tid&63;
  int lr = lane&15, lq = lane>>4;
#pragma unroll
  for (int r=0;r<4;r++){
    eps[w][lq*4+r][lr]    = ac0[r];
    eps[w][16+lq*4+r][lr] = ac1[r];
  }
  __syncthreads();
#pragma unroll
  for (int e=0;e<2;e++){
    int idx = e*256 + tid;
    int ml = idx>>4, j = idx&15;
    float gi = eps[0][ml][j] + bias[       j0+j];
    float gf = eps[1][ml][j] + bias[ 512 + j0+j];
    float gg = eps[2][ml][j] + bias[1024 + j0+j];
    float go = eps[3][ml][j] + bias[1536 + j0+j];
    int ci = (m0+ml)*512 + j0 + j;
    float c_ = cst[ci];
    float cn = sigm(gf)*c_ + sigm(gi)*tanh_(gg);
    float hn = sigm(go)*tanh_(cn);
    cst[ci] = cn;
    _Float16 hh = (_Float16)hn;
    h1p[(size_t)(m0+ml)*ldh1 + co1 + j0 + j] = hh;
    if (h2p) h2p[(size_t)(m0+ml)*ldh2 + co2 + j0 + j] = hh;
  }
}

// head + next-step attention, 256 threads, 16 seqs (R4 verbatim, no waits)
__device__ __forceinline__ void s3_body(const _Float16* __restrict__ h1, int ldh,
    const _Float16* __restrict__ Wf1, const float* __restrict__ bf1,
    const float* __restrict__ Wf2, const float* __restrict__ bf2,
    const float* __restrict__ M, const float* __restrict__ S,
    const float* __restrict__ bv2, _Float16* __restrict__ xn,
    float* __restrict__ out, int t, int n0,
    float (*hid)[264], float (*posL)[2], float (*denL)[4]){
  int tid = threadIdx.x, w = tid>>6, lane = tid&63;
  int lr = lane&15, lq = lane>>4;
  fx4 acc[4];
#pragma unroll
  for (int c=0;c<4;c++) acc[c] = (fx4){0.f,0.f,0.f,0.f};
  {
    const _Float16* ap = h1 + (size_t)(n0+lr)*ldh + lq*8;
    for (int ks=0; ks<16; ks++){
      hx8 a = *(const hx8*)(ap + ks*32);
#pragma unroll
      for (int c=0;c<4;c++){
        const _Float16* bp = Wf1 + (size_t)(w*64 + c*16 + lr)*512 + ks*32 + lq*8;
        acc[c] = __builtin_amdgcn_mfma_f32_16x16x32_f16(a, *(const hx8*)bp, acc[c], 0,0,0);
      }
    }
  }
#pragma unroll
  for (int c=0;c<4;c++)
#pragma unroll
    for (int r=0;r<4;r++){
      int col = w*64 + c*16 + lr;
      hid[lq*4+r][col] = fmaxf(acc[c][r] + bf1[col], 0.f);
    }
  __syncthreads();
  {
    int nn = tid>>4, o = (tid>>3)&1, sub = tid&7;
    float s = 0.f;
#pragma unroll
    for (int k2=0;k2<32;k2++) s += hid[nn][k2*8 + sub] * Wf2[o*256 + k2*8 + sub];
    s += __shfl_xor(s, 1, 64);
    s += __shfl_xor(s, 2, 64);
    s += __shfl_xor(s, 4, 64);
    if (sub==0){
      s += bf2[o];
      out[((size_t)(n0+nn)*TSTEPS + t)*2 + o] = s;
      posL[nn][o] = s;
      xn[(size_t)(n0+nn)*XC0 + o] = (_Float16)s;
    }
  }
  __syncthreads();
  if (tid < 64){
    int nn = tid>>2, h = tid&3;
    float p0 = posL[nn][0], p1 = posL[nn][1];
    int sb = (n0+nn)*24 + h*6;
    float den = S[sb] + p0*S[sb+1] + p1*S[sb+2] + p0*p0*S[sb+3] + p0*p1*S[sb+4] + p1*p1*S[sb+5];
    denL[nn][h] = 1.0f/den;
  }
  __syncthreads();
#pragma unroll
  for (int half=0; half<2; half++){
    int hd = half*256 + tid;
    int h = hd>>7, d = hd&127;
    for (int nn=0; nn<16; nn++){
      float p0 = posL[nn][0], p1 = posL[nn][1];
      float fa = p0*p0, fb = p0*p1, fc = p1*p1;
      const float* mp = M + (size_t)((n0+nn)*24 + h*6)*128 + d;
      float num = mp[0] + p0*mp[128] + p1*mp[256] + fa*mp[384] + fb*mp[512] + fc*mp[640];
      xn[(size_t)(n0+nn)*XC0 + 36 + hd] = (_Float16)(num*denL[nn][h] + bv2[hd]);
    }
  }
}

// ---------------- fallback (multi-launch, kernel-boundary coherence) -------

__global__ __launch_bounds__(256) void kgL0(const _Float16* __restrict__ x,
    const _Float16* __restrict__ B0, const float* __restrict__ b0,
    float* __restrict__ c0, _Float16* __restrict__ hin, _Float16* __restrict__ xnx){
  __shared__ __align__(16) char smem[32768];
  constexpr int ORD17[17] = {0,1,2,3,4,5,6,7,8,9,10,11,12,13,14,15,16};
  int bid = blockIdx.x, m0 = (bid>>5)*32, j0 = (bid&31)*16;
  fx4 ac0={0.f,0.f,0.f,0.f}, ac1={0.f,0.f,0.f,0.f};
  gates_core<17>(x, XC0, B0, XC0, ORD17, m0, j0, (_Float16*)smem, ac0, ac1);
  gates_epi((float(*)[32][16])(smem+24576), ac0, ac1, m0, j0, b0, c0,
            hin, XC1, 0, xnx, XC0, 576);
}

__global__ __launch_bounds__(256) void kgL1(const _Float16* __restrict__ h,
    const _Float16* __restrict__ B1, const float* __restrict__ b1,
    float* __restrict__ c1, _Float16* __restrict__ hnx){
  __shared__ __align__(16) char smem[32768];
  constexpr int ORD16[16] = {0,1,2,3,4,5,6,7,8,9,10,11,12,13,14,15};
  int bid = blockIdx.x, m0 = (bid>>5)*32, j0 = (bid&31)*16;
  fx4 ac0={0.f,0.f,0.f,0.f}, ac1={0.f,0.f,0.f,0.f};
  gates_core<16>(h, XC1, B1, XC1, ORD16, m0, j0, (_Float16*)smem, ac0, ac1);
  gates_epi((float(*)[32][16])(smem+24576), ac0, ac1, m0, j0, b1, c1,
            hnx, XC1, 512, (_Float16*)nullptr, 0, 0);
}

__global__ __launch_bounds__(256) void ks3b(const _Float16* __restrict__ h1, int ldh,
    const _Float16* __restrict__ Wf1, const float* __restrict__ bf1,
    const float* __restrict__ Wf2, const float* __restrict__ bf2,
    const float* __restrict__ M, const float* __restrict__ S,
    const float* __restrict__ bv2, _Float16* __restrict__ xn,
    float* __restrict__ out, int t){
  __shared__ float hid[16][264];
  __shared__ float posL[16][2];
  __shared__ float denL[16][4];
  s3_body(h1, ldh, Wf1, bf1, Wf2, bf2, M, S, bv2, xn, out, t,
          blockIdx.x*16, hid, posL, denL);
}

// ---------------- persistent loop kernel ----------------

// Group-local barrier primitives.  Arrival: one agent release-store
// (writes back this block's dirty lines).  Wait: 64 lanes relaxed-poll the
// group's flags, ballot; on success ONE acquire load (L1/L2 invalidate) so
// subsequent cached cross-block reads are fresh.  Transitive release->
// acquire chains cover every inter-step dependency (see R7 notes).
__device__ __forceinline__ void arrive_rel(unsigned* flag, unsigned val){
  __syncthreads();
  if (threadIdx.x == 0)
    __hip_atomic_store(flag, val, __ATOMIC_RELEASE, __HIP_MEMORY_SCOPE_AGENT);
}

__device__ __forceinline__ void acq_fence(const unsigned* p){
  unsigned d = __hip_atomic_load(p, __ATOMIC_ACQUIRE, __HIP_MEMORY_SCOPE_AGENT);
  asm volatile("" :: "v"(d));
}

// poll 32 consecutive flag lines starting at base
__device__ __forceinline__ void wait_group(unsigned* base, unsigned val){
  if (threadIdx.x < 64){
    const unsigned* p = base + (size_t)(threadIdx.x & 31)*FL;
    for(;;){
      unsigned v = __hip_atomic_load(p, __ATOMIC_RELAXED, __HIP_MEMORY_SCOPE_AGENT);
      if (__ballot(v >= val) == ~0ull) break;
      __builtin_amdgcn_s_sleep(1);
    }
    if (threadIdx.x == 0) acq_fence(base);
  }
  __syncthreads();
}

// poll the 2 s3 flags of group m
__device__ __forceinline__ void wait_s3(unsigned* s3f, int m, unsigned val){
  if (threadIdx.x < 64){
    const unsigned* p = s3f + (size_t)(2*m + (threadIdx.x & 1))*FL;
    for(;;){
      unsigned v = __hip_atomic_load(p, __ATOMIC_RELAXED, __HIP_MEMORY_SCOPE_AGENT);
      if (__ballot(v >= val) == ~0ull) break;
      __builtin_amdgcn_s_sleep(1);
    }
    if (threadIdx.x == 0) acq_fence(p);
  }
  __syncthreads();
}

struct LoopArgs {
  const _Float16* B0; const _Float16* B1;
  const float* b0; const float* b1;
  float* c0; float* c1;
  _Float16* x0; _Float16* x1; _Float16* h0; _Float16* h1;
  const _Float16* Wf1; const float* bf1; const float* Wf2; const float* bf2;
  const float* M; const float* S; const float* bv2;
  float* out; unsigned* bar;
};

// 640 blocks x 256 thr, 32KB LDS; >=3 blocks/CU co-resident (host-checked).
// All sync is 32-block (mblk) group-local + 2-flag s3 links; groups drift.
__global__ __launch_bounds__(256, 3) void kloop(LoopArgs a){
  __shared__ __align__(16) char smem[32768];
  _Float16* sbase = (_Float16*)smem;
  float (*eps)[32][16] = (float(*)[32][16])(smem + 24576);
  float (*hid)[264] = (float(*)[264])smem;
  float (*posL)[2] = (float(*)[2])(smem + 16896);
  float (*denL)[4] = (float(*)[4])(smem + 17024);
  constexpr int ORD_H0[8] = {9,10,11,12,13,14,15,16};
  constexpr int ORD_X[9]  = {0,1,2,3,4,5,6,7,8};
  constexpr int ORD16[16] = {0,1,2,3,4,5,6,7,8,9,10,11,12,13,14,15};
  int bid = blockIdx.x;
  int m = bid>>5, jb = bid&31;
  int m0 = m*32, j0 = jb*16;
  unsigned* L0own = a.bar + (size_t)bid*FL;
  unsigned* L1own = a.bar + (size_t)(640+bid)*FL;
  unsigned* gL0   = a.bar + (size_t)(m*32)*FL;
  unsigned* gL1   = a.bar + (size_t)(640+m*32)*FL;
  unsigned* s3f   = a.bar + (size_t)1280*FL;
  for (int t = 0; t < TSTEPS; ++t){
    _Float16* xin = (t&1) ? a.x1 : a.x0;
    _Float16* xnx = (t&1) ? a.x0 : a.x1;
    _Float16* hin = (t&1) ? a.h1 : a.h0;
    _Float16* hnx = (t&1) ? a.h0 : a.h1;
    fx4 ac0={0.f,0.f,0.f,0.f}, ac1={0.f,0.f,0.f,0.f};
    // layer 0: h0-half chunks first (ready since last step's L0 barrier)...
    gates_core<8>(xin, XC0, a.B0, XC0, ORD_H0, m0, j0, sbase, ac0, ac1);
    // ...then wait only on this group's two s3 flags before the x-half
    wait_s3(s3f, m, (unsigned)t);
    gates_core<9>(xin, XC0, a.B0, XC0, ORD_X, m0, j0, sbase, ac0, ac1);
    gates_epi(eps, ac0, ac1, m0, j0, a.b0, a.c0, hin, XC1, 0, xnx, XC0, 576);
    arrive_rel(L0own, (unsigned)(t+1));
    wait_group(gL0, (unsigned)(t+1));
    // layer 1
    ac0 = (fx4){0.f,0.f,0.f,0.f}; ac1 = (fx4){0.f,0.f,0.f,0.f};
    gates_core<16>(hin, XC1, a.B1, XC1, ORD16, m0, j0, sbase, ac0, ac1);
    gates_epi(eps, ac0, ac1, m0, j0, a.b1, a.c1, hnx, XC1, 512,
              (_Float16*)nullptr, 0, 0);
    arrive_rel(L1own, (unsigned)(t+1));
    // head + attention: jb 0/1 of each group, 16 seqs each
    if (jb < 2){
      wait_group(gL1, (unsigned)(t+1));
      s3_body(hnx + 512, XC1, a.Wf1, a.bf1, a.Wf2, a.bf2, a.M, a.S, a.bv2,
              xnx, a.out, t, m0 + jb*16, hid, posL, denL);
      arrive_rel(s3f + (size_t)(2*m+jb)*FL, (unsigned)(t+1));
    }
  }
}

// ---------------------------------------------------------------------------

extern "C" void kernel_launch(void* const* d_in, const int* in_sizes, int n_in,
                              void* d_out, int out_size, void* d_ws, size_t ws_size,
                              hipStream_t stream) {
  const float* ctx   = (const float*)d_in[0];
  const float* ipos  = (const float*)d_in[1];
  const float* ball  = (const float*)d_in[2];
  const int*   roles = (const int*)  d_in[3];
  const float* remb  = (const float*)d_in[5];
  const float* Wc    = (const float*)d_in[6];
  const float* bc    = (const float*)d_in[7];
  const float* Wq    = (const float*)d_in[8];
  const float* bq    = (const float*)d_in[9];
  const float* Wk    = (const float*)d_in[10];
  const float* bk    = (const float*)d_in[11];
  const float* Wv    = (const float*)d_in[12];
  const float* bv    = (const float*)d_in[13];
  const float* Wo    = (const float*)d_in[14];
  const float* bo    = (const float*)d_in[15];
  const float* Wih0  = (const float*)d_in[16];
  const float* Whh0  = (const float*)d_in[17];
  const float* bih0  = (const float*)d_in[18];
  const float* bhh0  = (const float*)d_in[19];
  const float* Wih1  = (const float*)d_in[20];
  const float* Whh1  = (const float*)d_in[21];
  const float* bih1  = (const float*)d_in[22];
  const float* bhh1  = (const float*)d_in[23];
  const float* Wf1   = (const float*)d_in[24];
  const float* bf1   = (const float*)d_in[25];
  const float* Wf2   = (const float*)d_in[26];
  const float* bf2   = (const float*)d_in[27];
  float* out = (float*)d_out;

  char* w = (char*)d_ws;
  auto alloc = [&](size_t bytes){ void* p = (void*)w; w += (bytes + 255) & ~(size_t)255; return p; };
  float* fY    = (float*)alloc(12*512*4);
  float* fcc   = (float*)alloc(12*4);
  float* fu    = (float*)alloc(3*512*4);
  float* fz    = (float*)alloc(12*512*4);
  float* fbv2  = (float*)alloc(512*4);
  float* fWcv  = (float*)alloc((size_t)512*512*4);
  float* fWcvT = (float*)alloc((size_t)512*512*4);
  float* fWmix = (float*)alloc((size_t)2048*512*4);
  _Float16* hB0  = (_Float16*)alloc((size_t)2048*XC0*2);
  _Float16* hB1  = (_Float16*)alloc((size_t)2048*XC1*2);
  _Float16* hWf1 = (_Float16*)alloc((size_t)256*512*2);
  float* fb0 = (float*)alloc(2048*4);
  float* fb1 = (float*)alloc(2048*4);
  float* fW6 = (float*)alloc((size_t)NSEQ*24*200*4);
  float* fS  = (float*)alloc((size_t)NSEQ*24*4);
  float* fF  = (float*)alloc((size_t)NSEQ*24*512*4);
  float* fM  = (float*)alloc((size_t)NSEQ*24*128*4);
  _Float16* xc0 = (_Float16*)alloc((size_t)NSEQ*XC0*2);
  _Float16* xc1 = (_Float16*)alloc((size_t)NSEQ*XC0*2);
  _Float16* hc0 = (_Float16*)alloc((size_t)NSEQ*XC1*2);
  _Float16* hc1 = (_Float16*)alloc((size_t)NSEQ*XC1*2);
  float* fc0 = (float*)alloc((size_t)NSEQ*512*4);
  float* fc1 = (float*)alloc((size_t)NSEQ*512*4);
  unsigned* bar = (unsigned*)alloc((size_t)1320*FL*4);

  // ---- folds ----
  kF1 <<<2,  256, 0, stream>>>(Wq, Wc, bc, bq, fu);
  kF2a<<<12, 512, 0, stream>>>(Wk, fu, fz);
  kF2b<<<12, 512, 0, stream>>>(fz, Wc, bc, bk, fu, fY, fcc);
  kFbv<<<2,  256, 0, stream>>>(Wv, bc, bv, fbv2);
  kgemm<<<dim3(8,8),  256, 0, stream>>>(Wv,   512, 0,  Wc, 512, fWcv,  512, 512);
  ktransp<<<1024, 256, 0, stream>>>(fWcv, fWcvT);
  kgemm<<<dim3(8,32), 256, 0, stream>>>(Wih0, 548, 36, Wo, 512, fWmix, 512, 512);
  kbcat0<<<2048, 256, 0, stream>>>(Wih0, fWmix, Whh0, hB0);
  kbcat1<<<2048, 256, 0, stream>>>(Wih1, Whh1, hB1);
  kcast<<<512,  256, 0, stream>>>(Wf1, hWf1, 256*512);
  kbias<<<8, 256, 0, stream>>>(Wih0, bo, bih0, bhh0, bih1, bhh1, fb0, fb1);

  // ---- moments ----
  kP1<<<NSEQ, 256, 0, stream>>>(ctx, fY, fcc, fW6);
  kP2<<<NSEQ, 256, 0, stream>>>(ctx, fW6, fF, fS);
  kP3<<<NSEQ*4, 128, 0, stream>>>(fF, fWcvT, fM);

  // ---- state init ----
  kinit<<<NSEQ, 512, 0, stream>>>(ball, roles, remb, xc0, xc1, hc0, hc1, fc0, fc1, bar);
  katt0<<<NSEQ, 128, 0, stream>>>(ipos, fM, fS, fbv2, xc0);

  // ---- recurrent loop: persistent kernel if co-residency is provable ----
  int maxb = 0;
  hipError_t qe = hipOccupancyMaxActiveBlocksPerMultiprocessor(
      &maxb, reinterpret_cast<const void*>(kloop), 256, 0);
  if (qe == hipSuccess && maxb >= 3){
    LoopArgs la;
    la.B0 = hB0; la.B1 = hB1; la.b0 = fb0; la.b1 = fb1;
    la.c0 = fc0; la.c1 = fc1;
    la.x0 = xc0; la.x1 = xc1; la.h0 = hc0; la.h1 = hc1;
    la.Wf1 = hWf1; la.bf1 = bf1; la.Wf2 = Wf2; la.bf2 = bf2;
    la.M = fM; la.S = fS; la.bv2 = fbv2; la.out = out; la.bar = bar;
    kloop<<<NBLK, 256, 0, stream>>>(la);
  } else {
    for (int t = 0; t < TSTEPS; ++t){
      _Float16* xin  = (t&1) ? xc1 : xc0;
      _Float16* xnx  = (t&1) ? xc0 : xc1;
      _Float16* hin  = (t&1) ? hc1 : hc0;
      _Float16* hnx  = (t&1) ? hc0 : hc1;
      kgL0<<<640, 256, 0, stream>>>(xin, hB0, fb0, fc0, hin, xnx);
      kgL1<<<640, 256, 0, stream>>>(hin, hB1, fb1, fc1, hnx);
      ks3b<<<40, 256, 0, stream>>>(hnx + 512, XC1, hWf1, bf1, Wf2, bf2,
                                   fM, fS, fbv2, xnx, out, t);
    }
  }
}